// Round 7
// baseline (3218.179 us; speedup 1.0000x reference)
//
#include <hip/hip_runtime.h>

#define TT 4096          // signal length
#define NN 8192          // padded length
#define NF 4096          // FFT length = 16^3

// XOR swizzle: permutes low 4 bits by a hash of the row; measured ~2% LDS
// bank-conflict overhead across all access patterns used here.
#define SW(i) ((i) ^ ((((i) >> 4) ^ ((i) >> 8)) & 15))

// hardware sin/cos of 2*pi*x (x in revolutions); args here are exact dyadics
__device__ __forceinline__ float sin2pi(float x) { return __builtin_amdgcn_sinf(x); }
__device__ __forceinline__ float cos2pi(float x) { return __builtin_amdgcn_cosf(x); }

// (ar,ai) *= (br,bi)
#define WMUL(ar, ai, br, bi) { float _t = (ar)*(br) - (ai)*(bi); \
                               (ai) = (ar)*(bi) + (ai)*(br); (ar) = _t; }

// e^{i*2*pi/32} — step for k -> k+256 at N=8192
#define C32 0.9807852804032304f
#define S32 0.19509032201612825f

// -------------------- register DFT16 (two radix-4 layers, DIT) --------------
// S = -1: forward (e^{-i}), S = +1: inverse (e^{+i}).
template<int S>
__device__ __forceinline__ void dft4(float& ar, float& ai, float& br, float& bi,
                                     float& cr, float& ci, float& er, float& ei) {
    float t0r = ar + cr, t0i = ai + ci;
    float t1r = ar - cr, t1i = ai - ci;
    float t2r = br + er, t2i = bi + ei;
    float t3r = br - er, t3i = bi - ei;
    ar = t0r + t2r; ai = t0i + t2i;
    cr = t0r - t2r; ci = t0i - t2i;
    br = t1r - S * t3i; bi = t1i + S * t3r;
    er = t1r + S * t3i; ei = t1i - S * t3r;
}

#define DFT16_TMULS(S, xr, xi) { \
    const float C1 = 0.9238795325112867f; \
    const float S1 = 0.3826834323650898f; \
    const float R2 = 0.7071067811865476f; \
    { float _r = xr[5]*(C1) - xi[5]*(S*S1);  xi[5]  = xr[5]*(S*S1)  + xi[5]*(C1);  xr[5]  = _r; } \
    { float _r = xr[9]*(R2) - xi[9]*(S*R2);  xi[9]  = xr[9]*(S*R2)  + xi[9]*(R2);  xr[9]  = _r; } \
    { float _r = xr[13]*(S1) - xi[13]*(S*C1); xi[13] = xr[13]*(S*C1) + xi[13]*(S1); xr[13] = _r; } \
    { float _r = xr[6]*(R2) - xi[6]*(S*R2);  xi[6]  = xr[6]*(S*R2)  + xi[6]*(R2);  xr[6]  = _r; } \
    { float _r = -S * xi[10]; xi[10] = S * xr[10]; xr[10] = _r; } \
    { float _r = xr[14]*(-R2) - xi[14]*(S*R2); xi[14] = xr[14]*(S*R2) + xi[14]*(-R2); xr[14] = _r; } \
    { float _r = xr[7]*(S1) - xi[7]*(S*C1);  xi[7]  = xr[7]*(S*C1)  + xi[7]*(S1);  xr[7]  = _r; } \
    { float _r = xr[11]*(-R2) - xi[11]*(S*R2); xi[11] = xr[11]*(S*R2) + xi[11]*(-R2); xr[11] = _r; } \
    { float _r = xr[15]*(-C1) - xi[15]*(-S*S1); xi[15] = xr[15]*(-S*S1) + xi[15]*(-C1); xr[15] = _r; } }

template<int S>
__device__ __forceinline__ void dft16(float xr[16], float xi[16]) {
    #pragma unroll
    for (int n0 = 0; n0 < 4; ++n0)
        dft4<S>(xr[n0], xi[n0], xr[n0 + 4], xi[n0 + 4],
                xr[n0 + 8], xi[n0 + 8], xr[n0 + 12], xi[n0 + 12]);

    DFT16_TMULS(S, xr, xi)

    #pragma unroll
    for (int k0 = 0; k0 < 4; ++k0)
        dft4<S>(xr[4*k0], xi[4*k0], xr[4*k0+1], xi[4*k0+1],
                xr[4*k0+2], xi[4*k0+2], xr[4*k0+3], xi[4*k0+3]);

    float tr[16], ti[16];
    #pragma unroll
    for (int q = 0; q < 16; ++q) { int p = 4*(q & 3) + (q >> 2); tr[q] = xr[p]; ti[q] = xi[p]; }
    #pragma unroll
    for (int q = 0; q < 16; ++q) { xr[q] = tr[q]; xi[q] = ti[q]; }
}

// Post-DFT twiddle: x[q] *= w^q with w given by (w1r,w1i); exact reset to
// w^8 = (w8r,w8i) at the midpoint caps the recurrence chain at 7 muls.
__device__ __forceinline__ void twiddle16(float xr[16], float xi[16],
                                          float w1r, float w1i,
                                          float w8r, float w8i) {
    float wr = w1r, wi = w1i;
    #pragma unroll
    for (int q = 1; q < 16; ++q) {
        float _r = xr[q]*wr - xi[q]*wi;
        xi[q] = xr[q]*wi + xi[q]*wr; xr[q] = _r;
        if (q == 7) { wr = w8r; wi = w8i; }
        else        { WMUL(wr, wi, w1r, w1i) }
    }
}

// Pruned final-stage DFT16: only natural outputs q in [4,12) are ever needed.
// Output transpose p = 4*(q&3)+(q>>2) means we need only the "b" (q=4+k0) and
// "c" (q=8+k0) outputs of each second-layer dft4.
template<int S>
__device__ __forceinline__ void dft16_mid8(float xr[16], float xi[16],
                                           float yr[8], float yi[8]) {
    #pragma unroll
    for (int n0 = 0; n0 < 4; ++n0)
        dft4<S>(xr[n0], xi[n0], xr[n0 + 4], xi[n0 + 4],
                xr[n0 + 8], xi[n0 + 8], xr[n0 + 12], xi[n0 + 12]);

    DFT16_TMULS(S, xr, xi)

    #pragma unroll
    for (int k0 = 0; k0 < 4; ++k0) {
        float ar = xr[4*k0],     ai = xi[4*k0];
        float br = xr[4*k0 + 1], bi = xi[4*k0 + 1];
        float cr = xr[4*k0 + 2], ci = xi[4*k0 + 2];
        float er = xr[4*k0 + 3], ei = xi[4*k0 + 3];
        float t0r = ar + cr, t0i = ai + ci;
        float t1r = ar - cr, t1i = ai - ci;
        float t2r = br + er, t2i = bi + ei;
        float t3r = br - er, t3i = bi - ei;
        yr[k0]     = t1r - S * t3i;  yi[k0]     = t1i + S * t3r;  // natural q = 4+k0
        yr[4 + k0] = t0r - t2r;      yi[4 + k0] = t0i - t2i;      // natural q = 8+k0
    }
}

__device__ __forceinline__ int refl(int p) {
    if (p < 2048) return 2047 - p;
    if (p < 6144) return p - 2048;
    return 10239 - p;
}

// -------------------- forward: real-8192 FFT via packed complex-4096 ---------
__global__ __launch_bounds__(256) void fwd_kernel(const float* __restrict__ in,
                                                  float2* __restrict__ F) {
    __shared__ float2 lds[NF];
    const int b = blockIdx.x, tid = threadIdx.x;
    const float* row = in + b * TT;

    float xr[16], xi[16];

    // ---- staging + stage 0 (stride 256), fused in registers ----
    #pragma unroll
    for (int r = 0; r < 16; ++r) {
        const int i = tid + 256 * r;
        xr[r] = row[refl(2 * i)];
        xi[r] = row[refl(2 * i + 1)];
    }
    dft16<-1>(xr, xi);
    twiddle16(xr, xi,
              cos2pi((float)tid * (1.0f / 4096.0f)), -sin2pi((float)tid * (1.0f / 4096.0f)),
              cos2pi((float)tid * (1.0f / 512.0f)),  -sin2pi((float)tid * (1.0f / 512.0f)));
    #pragma unroll
    for (int q = 0; q < 16; ++q) lds[SW(tid + 256 * q)] = make_float2(xr[q], xi[q]);
    __syncthreads();

    // ---- stage 1 (stride 16) ----
    {
        const int j = tid & 15;
        const int base = ((tid >> 4) << 8) + j;
        #pragma unroll
        for (int q = 0; q < 16; ++q) {
            float2 v = lds[SW(base + 16 * q)];
            xr[q] = v.x; xi[q] = v.y;
        }
        dft16<-1>(xr, xi);
        twiddle16(xr, xi,
                  cos2pi((float)j * (1.0f / 256.0f)), -sin2pi((float)j * (1.0f / 256.0f)),
                  cos2pi((float)j * (1.0f / 32.0f)),  -sin2pi((float)j * (1.0f / 32.0f)));
        #pragma unroll
        for (int q = 0; q < 16; ++q) lds[SW(base + 16 * q)] = make_float2(xr[q], xi[q]);
    }
    __syncthreads();

    // ---- stage 2 (twiddle-free) + natural-order scatter ----
    {
        const int base = tid << 4;
        const int f2 = (tid ^ (tid >> 4)) & 15;
        #pragma unroll
        for (int q = 0; q < 16; ++q) {
            float2 v = lds[base + (q ^ f2)];
            xr[q] = v.x; xi[q] = v.y;
        }
        dft16<-1>(xr, xi);
        __syncthreads();
        const int c = tid & 15;
        const int h = tid >> 4;
        #pragma unroll
        for (int q = 0; q < 16; ++q)
            lds[(q << 8) + (c << 4) + (h ^ c ^ q)] = make_float2(xr[q], xi[q]);
    }
    __syncthreads();

    // ---- epilogue: unpack real FFT; twiddle (c,s) by recurrence over r ----
    {
        const float c0 = cos2pi((float)(tid + 1) * (1.0f / 8192.0f));
        const float s0 = sin2pi((float)(tid + 1) * (1.0f / 8192.0f));
        float cc = c0, ss = s0;
        #pragma unroll
        for (int r = 0; r < 16; ++r) {
            const int i = tid + 256 * r;
            const int k = i + 1;
            const float2 za = lds[SW(k & (NF - 1))];
            const float2 zb = lds[SW((NF - k) & (NF - 1))];
            const float fer = 0.5f * (za.x + zb.x), fei = 0.5f * (za.y - zb.y);
            const float fo_r = 0.5f * (za.y + zb.y), fo_i = -0.5f * (za.x - zb.x);
            F[b * NF + i] = make_float2(fer + cc * fo_r + ss * fo_i,
                                        fei + cc * fo_i - ss * fo_r);
            if (r == 7) { cc = -s0; ss = c0; }        // exact: * e^{i*pi/2}
            else        { WMUL(cc, ss, C32, S32) }
        }
    }
}

// -------------------- inverse: one block per (batch, scale) ------------------
// d_k = F[b,k]*wft[j,k+1]; half-band 8192-IFFT = two 4096-IFFTs computed
// TOGETHER as one 2-vector FFT (signal0 = even samples, signal1 = odd).
// R7 = R2 body (best measured structure: VGPR 96, no spill, 2 barriers,
// stage-2 fused with epilogue) + the R6-validated band-limit skip: wft[j] is
// a Gaussian active only for |scale*omega - 6| <= 5.5, scale = 2*2^((15+j)/16)
// (derived from build()); skipped bins have wft < 5.5e-7 -> log-output error
// < 1e-5 (absmax measured unchanged at 0.03125 in R6).  Chunks r > R1 are
// exact zeros: loads and rotate math skipped via block-uniform branch.
__global__ __launch_bounds__(256) void inv_kernel(const float2* __restrict__ F,
                                                  const float* __restrict__ wft,
                                                  float* __restrict__ out,
                                                  int NS) {
    __shared__ float4 lds[NF];                 // 64 KB -> 2 blocks/CU
    const int blk = blockIdx.x;
    const int b = blk / NS;
    const int j = blk - b * NS;
    const int tid = threadIdx.x;

    const float2* Frow = F + b * NF;
    const float* wrow = wft + (size_t)j * NN + 1;
    float* orow = out + (size_t)(b * NS + j) * TT;
    const float LOGN = 9.0109131020007136f;       // log(8192)
    const float HALF_LN2 = 0.34657359027997264f;  // 0.5 * ln(2)

    // ---- band bound (block-uniform): last active 256-bin chunk ----
    const float scale = 2.0f * exp2f((float)(15 + j) * 0.0625f);
    int khi = (int)(14993.7f / scale) + 2;        // (6+5.5)*8192/(2*pi), expanded
    if (khi > 4095) khi = 4095;
    const int R1 = khi >> 8;                      // in [0,15]; 15 -> no skip

    float xr0[16], xi0[16], xr1[16], xi1[16];

    #define CMUL2(q, wr, wi) { \
        float _r0 = xr0[q]*(wr) - xi0[q]*(wi); xi0[q] = xr0[q]*(wi) + xi0[q]*(wr); xr0[q] = _r0; \
        float _r1 = xr1[q]*(wr) - xi1[q]*(wi); xi1[q] = xr1[q]*(wi) + xi1[q]*(wr); xr1[q] = _r1; }

    // ---- staging + stage 0 (stride 256), fused in registers ----
    // d0 = F*w ; d1 = d0 * e^{+2*pi*i*k/8192}, k = tid + 256*r.
    // Twiddle advances by exact e^{i*2pi/32} per r; exact e^{i*pi/2} reset at r=8.
    {
        const float c0 = cos2pi((float)tid * (1.0f / 8192.0f));
        const float s0 = sin2pi((float)tid * (1.0f / 8192.0f));
        float cr = c0, ci = s0;
        #pragma unroll
        for (int r = 0; r < 16; ++r) {
            if (r <= R1) {
                const int k = tid + 256 * r;
                const float2 f = Frow[k];
                const float w = wrow[k];
                const float d0r = f.x * w, d0i = f.y * w;
                xr0[r] = d0r; xi0[r] = d0i;
                xr1[r] = d0r * cr - d0i * ci;
                xi1[r] = d0r * ci + d0i * cr;
                if (r == 7) { cr = -s0; ci = c0; }
                else        { WMUL(cr, ci, C32, S32) }
            } else {
                xr0[r] = 0.0f; xi0[r] = 0.0f; xr1[r] = 0.0f; xi1[r] = 0.0f;
            }
        }
    }
    dft16<1>(xr0, xi0);
    dft16<1>(xr1, xi1);
    {
        const float w1r = cos2pi((float)tid * (1.0f / 4096.0f));
        const float w1i = sin2pi((float)tid * (1.0f / 4096.0f));
        const float w8r = cos2pi((float)tid * (1.0f / 512.0f));
        const float w8i = sin2pi((float)tid * (1.0f / 512.0f));
        float wr = w1r, wi = w1i;
        #pragma unroll
        for (int q = 1; q < 16; ++q) {
            CMUL2(q, wr, wi)
            if (q == 7) { wr = w8r; wi = w8i; }
            else        { WMUL(wr, wi, w1r, w1i) }
        }
    }
    #pragma unroll
    for (int q = 0; q < 16; ++q)
        lds[SW(tid + 256 * q)] = make_float4(xr0[q], xi0[q], xr1[q], xi1[q]);
    __syncthreads();

    // ---- stage 1: stride 16, jj = tid&15 ----
    {
        const int jj = tid & 15;
        const int base = ((tid >> 4) << 8) + jj;
        #pragma unroll
        for (int q = 0; q < 16; ++q) {
            float4 v = lds[SW(base + 16 * q)];
            xr0[q] = v.x; xi0[q] = v.y; xr1[q] = v.z; xi1[q] = v.w;
        }
        dft16<1>(xr0, xi0);
        dft16<1>(xr1, xi1);
        const float w1r = cos2pi((float)jj * (1.0f / 256.0f));
        const float w1i = sin2pi((float)jj * (1.0f / 256.0f));
        const float w8r = cos2pi((float)jj * (1.0f / 32.0f));
        const float w8i = sin2pi((float)jj * (1.0f / 32.0f));
        float wr = w1r, wi = w1i;
        #pragma unroll
        for (int q = 1; q < 16; ++q) {
            CMUL2(q, wr, wi)
            if (q == 7) { wr = w8r; wi = w8i; }
            else        { WMUL(wr, wi, w1r, w1i) }
        }
        #pragma unroll
        for (int q = 0; q < 16; ++q)
            lds[SW(base + 16 * q)] = make_float4(xr0[q], xi0[q], xr1[q], xi1[q]);
    }
    __syncthreads();

    // ---- stage 2 fused with epilogue ----
    // Thread t runs the butterfly of former-thread ns = nibbleswap(t); that
    // butterfly's natural outputs are n = q*256 + (ns&15)*16 + (ns>>4)
    //                               = q*256 + t,  q = 4+i2 after pruning.
    // So y[i2] IS the value for orow float2 slot [t + 256*i2] -- store direct.
    {
        const int ns = ((tid & 15) << 4) | (tid >> 4);   // nibble-swap
        const int base = ns << 4;
        const int f2 = (ns ^ (ns >> 4)) & 15;
        #pragma unroll
        for (int q = 0; q < 16; ++q) {
            float4 v = lds[base + (q ^ f2)];             // == lds[SW(base+q)]
            xr0[q] = v.x; xi0[q] = v.y; xr1[q] = v.z; xi1[q] = v.w;
        }
        float yr0[8], yi0[8], yr1[8], yi1[8];
        dft16_mid8<1>(xr0, xi0, yr0, yi0);
        dft16_mid8<1>(xr1, xi1, yr1, yi1);
        #pragma unroll
        for (int i2 = 0; i2 < 8; ++i2) {
            const float m0 = yr0[i2] * yr0[i2] + yi0[i2] * yi0[i2];
            const float m1 = yr1[i2] * yr1[i2] + yi1[i2] * yi1[i2];
            const float v0 = HALF_LN2 * __builtin_amdgcn_logf(m0) - LOGN;
            const float v1 = HALF_LN2 * __builtin_amdgcn_logf(m1) - LOGN;
            ((float2*)orow)[tid + 256 * i2] = make_float2(v0, v1);
        }
    }
    #undef CMUL2
}

extern "C" void kernel_launch(void* const* d_in, const int* in_sizes, int n_in,
                              void* d_out, int out_size, void* d_ws, size_t ws_size,
                              hipStream_t stream) {
    const float* inputs = (const float*)d_in[0];
    const float* wft = (const float*)d_in[1];
    float* out = (float*)d_out;

    const int B = in_sizes[0] / TT;     // 64
    const int NS = in_sizes[1] / NN;    // 75

    float2* F = (float2*)d_ws;          // B*4096 complex = 2 MB

    hipLaunchKernelGGL(fwd_kernel, dim3(B), dim3(256), 0, stream, inputs, F);
    hipLaunchKernelGGL(inv_kernel, dim3(B * NS), dim3(256), 0, stream, F, wft, out, NS);
}

// Round 8
// 374.677 us; speedup vs baseline: 8.5892x; 8.5892x over previous
//
#include <hip/hip_runtime.h>

#define TT 4096          // signal length
#define NN 8192          // padded length
#define NF 4096          // FFT length = 16^3

// XOR swizzle: permutes low 4 bits by a hash of the row; measured ~2% LDS
// bank-conflict overhead across all access patterns used here.
#define SW(i) ((i) ^ ((((i) >> 4) ^ ((i) >> 8)) & 15))

// hardware sin/cos of 2*pi*x (x in revolutions); args here are exact dyadics
__device__ __forceinline__ float sin2pi(float x) { return __builtin_amdgcn_sinf(x); }
__device__ __forceinline__ float cos2pi(float x) { return __builtin_amdgcn_cosf(x); }

// (ar,ai) *= (br,bi)
#define WMUL(ar, ai, br, bi) { float _t = (ar)*(br) - (ai)*(bi); \
                               (ai) = (ar)*(bi) + (ai)*(br); (ar) = _t; }

// e^{i*2*pi/32} — step for k -> k+256 at N=8192
#define C32 0.9807852804032304f
#define S32 0.19509032201612825f

// -------------------- register DFT16 (two radix-4 layers, DIT) --------------
// S = -1: forward (e^{-i}), S = +1: inverse (e^{+i}).
template<int S>
__device__ __forceinline__ void dft4(float& ar, float& ai, float& br, float& bi,
                                     float& cr, float& ci, float& er, float& ei) {
    float t0r = ar + cr, t0i = ai + ci;
    float t1r = ar - cr, t1i = ai - ci;
    float t2r = br + er, t2i = bi + ei;
    float t3r = br - er, t3i = bi - ei;
    ar = t0r + t2r; ai = t0i + t2i;
    cr = t0r - t2r; ci = t0i - t2i;
    br = t1r - S * t3i; bi = t1i + S * t3r;
    er = t1r + S * t3i; ei = t1i - S * t3r;
}

#define DFT16_TMULS(S, xr, xi) { \
    const float C1 = 0.9238795325112867f; \
    const float S1 = 0.3826834323650898f; \
    const float R2 = 0.7071067811865476f; \
    { float _r = xr[5]*(C1) - xi[5]*(S*S1);  xi[5]  = xr[5]*(S*S1)  + xi[5]*(C1);  xr[5]  = _r; } \
    { float _r = xr[9]*(R2) - xi[9]*(S*R2);  xi[9]  = xr[9]*(S*R2)  + xi[9]*(R2);  xr[9]  = _r; } \
    { float _r = xr[13]*(S1) - xi[13]*(S*C1); xi[13] = xr[13]*(S*C1) + xi[13]*(S1); xr[13] = _r; } \
    { float _r = xr[6]*(R2) - xi[6]*(S*R2);  xi[6]  = xr[6]*(S*R2)  + xi[6]*(R2);  xr[6]  = _r; } \
    { float _r = -S * xi[10]; xi[10] = S * xr[10]; xr[10] = _r; } \
    { float _r = xr[14]*(-R2) - xi[14]*(S*R2); xi[14] = xr[14]*(S*R2) + xi[14]*(-R2); xr[14] = _r; } \
    { float _r = xr[7]*(S1) - xi[7]*(S*C1);  xi[7]  = xr[7]*(S*C1)  + xi[7]*(S1);  xr[7]  = _r; } \
    { float _r = xr[11]*(-R2) - xi[11]*(S*R2); xi[11] = xr[11]*(S*R2) + xi[11]*(-R2); xr[11] = _r; } \
    { float _r = xr[15]*(-C1) - xi[15]*(-S*S1); xi[15] = xr[15]*(-S*S1) + xi[15]*(-C1); xr[15] = _r; } }

template<int S>
__device__ __forceinline__ void dft16(float xr[16], float xi[16]) {
    #pragma unroll
    for (int n0 = 0; n0 < 4; ++n0)
        dft4<S>(xr[n0], xi[n0], xr[n0 + 4], xi[n0 + 4],
                xr[n0 + 8], xi[n0 + 8], xr[n0 + 12], xi[n0 + 12]);

    DFT16_TMULS(S, xr, xi)

    #pragma unroll
    for (int k0 = 0; k0 < 4; ++k0)
        dft4<S>(xr[4*k0], xi[4*k0], xr[4*k0+1], xi[4*k0+1],
                xr[4*k0+2], xi[4*k0+2], xr[4*k0+3], xi[4*k0+3]);

    float tr[16], ti[16];
    #pragma unroll
    for (int q = 0; q < 16; ++q) { int p = 4*(q & 3) + (q >> 2); tr[q] = xr[p]; ti[q] = xi[p]; }
    #pragma unroll
    for (int q = 0; q < 16; ++q) { xr[q] = tr[q]; xi[q] = ti[q]; }
}

// Post-DFT twiddle: x[q] *= w^q with w given by (w1r,w1i); exact reset to
// w^8 = (w8r,w8i) at the midpoint caps the recurrence chain at 7 muls.
__device__ __forceinline__ void twiddle16(float xr[16], float xi[16],
                                          float w1r, float w1i,
                                          float w8r, float w8i) {
    float wr = w1r, wi = w1i;
    #pragma unroll
    for (int q = 1; q < 16; ++q) {
        float _r = xr[q]*wr - xi[q]*wi;
        xi[q] = xr[q]*wi + xi[q]*wr; xr[q] = _r;
        if (q == 7) { wr = w8r; wi = w8i; }
        else        { WMUL(wr, wi, w1r, w1i) }
    }
}

// Pruned final-stage DFT16: only natural outputs q in [4,12) are ever needed.
// Output transpose p = 4*(q&3)+(q>>2) means we need only the "b" (q=4+k0) and
// "c" (q=8+k0) outputs of each second-layer dft4.
template<int S>
__device__ __forceinline__ void dft16_mid8(float xr[16], float xi[16],
                                           float yr[8], float yi[8]) {
    #pragma unroll
    for (int n0 = 0; n0 < 4; ++n0)
        dft4<S>(xr[n0], xi[n0], xr[n0 + 4], xi[n0 + 4],
                xr[n0 + 8], xi[n0 + 8], xr[n0 + 12], xi[n0 + 12]);

    DFT16_TMULS(S, xr, xi)

    #pragma unroll
    for (int k0 = 0; k0 < 4; ++k0) {
        float ar = xr[4*k0],     ai = xi[4*k0];
        float br = xr[4*k0 + 1], bi = xi[4*k0 + 1];
        float cr = xr[4*k0 + 2], ci = xi[4*k0 + 2];
        float er = xr[4*k0 + 3], ei = xi[4*k0 + 3];
        float t0r = ar + cr, t0i = ai + ci;
        float t1r = ar - cr, t1i = ai - ci;
        float t2r = br + er, t2i = bi + ei;
        float t3r = br - er, t3i = bi - ei;
        yr[k0]     = t1r - S * t3i;  yi[k0]     = t1i + S * t3r;  // natural q = 4+k0
        yr[4 + k0] = t0r - t2r;      yi[4 + k0] = t0i - t2i;      // natural q = 8+k0
    }
}

__device__ __forceinline__ int refl(int p) {
    if (p < 2048) return 2047 - p;
    if (p < 6144) return p - 2048;
    return 10239 - p;
}

// -------------------- fwd task: real-8192 FFT via packed complex-4096 --------
// Verbatim R2 math (96 VGPR standalone); NO conditionals in the staging loop.
__device__ void fwd_body(const float* __restrict__ in, float2* __restrict__ F,
                         float2* lds, int b, int tid) {
    const float* row = in + b * TT;
    float xr[16], xi[16];

    #pragma unroll
    for (int r = 0; r < 16; ++r) {
        const int i = tid + 256 * r;
        xr[r] = row[refl(2 * i)];
        xi[r] = row[refl(2 * i + 1)];
    }
    dft16<-1>(xr, xi);
    twiddle16(xr, xi,
              cos2pi((float)tid * (1.0f / 4096.0f)), -sin2pi((float)tid * (1.0f / 4096.0f)),
              cos2pi((float)tid * (1.0f / 512.0f)),  -sin2pi((float)tid * (1.0f / 512.0f)));
    #pragma unroll
    for (int q = 0; q < 16; ++q) lds[SW(tid + 256 * q)] = make_float2(xr[q], xi[q]);
    __syncthreads();

    {
        const int j = tid & 15;
        const int base = ((tid >> 4) << 8) + j;
        #pragma unroll
        for (int q = 0; q < 16; ++q) {
            float2 v = lds[SW(base + 16 * q)];
            xr[q] = v.x; xi[q] = v.y;
        }
        dft16<-1>(xr, xi);
        twiddle16(xr, xi,
                  cos2pi((float)j * (1.0f / 256.0f)), -sin2pi((float)j * (1.0f / 256.0f)),
                  cos2pi((float)j * (1.0f / 32.0f)),  -sin2pi((float)j * (1.0f / 32.0f)));
        #pragma unroll
        for (int q = 0; q < 16; ++q) lds[SW(base + 16 * q)] = make_float2(xr[q], xi[q]);
    }
    __syncthreads();

    {
        const int base = tid << 4;
        const int f2 = (tid ^ (tid >> 4)) & 15;
        #pragma unroll
        for (int q = 0; q < 16; ++q) {
            float2 v = lds[base + (q ^ f2)];
            xr[q] = v.x; xi[q] = v.y;
        }
        dft16<-1>(xr, xi);
        __syncthreads();
        const int c = tid & 15;
        const int h = tid >> 4;
        #pragma unroll
        for (int q = 0; q < 16; ++q)
            lds[(q << 8) + (c << 4) + (h ^ c ^ q)] = make_float2(xr[q], xi[q]);
    }
    __syncthreads();

    {
        const float c0 = cos2pi((float)(tid + 1) * (1.0f / 8192.0f));
        const float s0 = sin2pi((float)(tid + 1) * (1.0f / 8192.0f));
        float cc = c0, ss = s0;
        #pragma unroll
        for (int r = 0; r < 16; ++r) {
            const int i = tid + 256 * r;
            const int k = i + 1;
            const float2 za = lds[SW(k & (NF - 1))];
            const float2 zb = lds[SW((NF - k) & (NF - 1))];
            const float fer = 0.5f * (za.x + zb.x), fei = 0.5f * (za.y - zb.y);
            const float fo_r = 0.5f * (za.y + zb.y), fo_i = -0.5f * (za.x - zb.x);
            F[b * NF + i] = make_float2(fer + cc * fo_r + ss * fo_i,
                                        fei + cc * fo_i - ss * fo_r);
            if (r == 7) { cc = -s0; ss = c0; }        // exact: * e^{i*pi/2}
            else        { WMUL(cc, ss, C32, S32) }
        }
    }
}

// -------------------- inv task: one (batch, scale) pair ----------------------
// Verbatim R2 float4 dual-signal body (96 VGPR standalone, no spill): branch-
// free staging, 2 barriers, stage-2 fused with the epilogue via nibble-swap.
// The band-limit skip is permanently removed (R7: its per-r conditional blew
// VGPR 96 -> 256 and spilled 16 GB of scratch traffic).
__device__ void inv_body(const float2* __restrict__ F, const float* __restrict__ wft,
                         float* __restrict__ out, float4* lds,
                         int b, int j, int tid, int NS) {
    const float2* Frow = F + b * NF;
    const float* wrow = wft + (size_t)j * NN + 1;
    float* orow = out + (size_t)(b * NS + j) * TT;
    const float LOGN = 9.0109131020007136f;       // log(8192)
    const float HALF_LN2 = 0.34657359027997264f;  // 0.5 * ln(2)

    float xr0[16], xi0[16], xr1[16], xi1[16];

    #define CMUL2(q, wr, wi) { \
        float _r0 = xr0[q]*(wr) - xi0[q]*(wi); xi0[q] = xr0[q]*(wi) + xi0[q]*(wr); xr0[q] = _r0; \
        float _r1 = xr1[q]*(wr) - xi1[q]*(wi); xi1[q] = xr1[q]*(wi) + xi1[q]*(wr); xr1[q] = _r1; }

    // ---- staging + stage 0 (stride 256), fused in registers ----
    // d0 = F*w ; d1 = d0 * e^{+2*pi*i*k/8192}, k = tid + 256*r.
    // Twiddle advances by exact e^{i*2pi/32} per r; exact e^{i*pi/2} reset at r=8.
    {
        const float c0 = cos2pi((float)tid * (1.0f / 8192.0f));
        const float s0 = sin2pi((float)tid * (1.0f / 8192.0f));
        float cr = c0, ci = s0;
        #pragma unroll
        for (int r = 0; r < 16; ++r) {
            const int k = tid + 256 * r;
            const float2 f = Frow[k];
            const float w = wrow[k];
            const float d0r = f.x * w, d0i = f.y * w;
            xr0[r] = d0r; xi0[r] = d0i;
            xr1[r] = d0r * cr - d0i * ci;
            xi1[r] = d0r * ci + d0i * cr;
            if (r == 7) { cr = -s0; ci = c0; }
            else        { WMUL(cr, ci, C32, S32) }
        }
    }
    dft16<1>(xr0, xi0);
    dft16<1>(xr1, xi1);
    {
        const float w1r = cos2pi((float)tid * (1.0f / 4096.0f));
        const float w1i = sin2pi((float)tid * (1.0f / 4096.0f));
        const float w8r = cos2pi((float)tid * (1.0f / 512.0f));
        const float w8i = sin2pi((float)tid * (1.0f / 512.0f));
        float wr = w1r, wi = w1i;
        #pragma unroll
        for (int q = 1; q < 16; ++q) {
            CMUL2(q, wr, wi)
            if (q == 7) { wr = w8r; wi = w8i; }
            else        { WMUL(wr, wi, w1r, w1i) }
        }
    }
    #pragma unroll
    for (int q = 0; q < 16; ++q)
        lds[SW(tid + 256 * q)] = make_float4(xr0[q], xi0[q], xr1[q], xi1[q]);
    __syncthreads();

    // ---- stage 1: stride 16, jj = tid&15 ----
    {
        const int jj = tid & 15;
        const int base = ((tid >> 4) << 8) + jj;
        #pragma unroll
        for (int q = 0; q < 16; ++q) {
            float4 v = lds[SW(base + 16 * q)];
            xr0[q] = v.x; xi0[q] = v.y; xr1[q] = v.z; xi1[q] = v.w;
        }
        dft16<1>(xr0, xi0);
        dft16<1>(xr1, xi1);
        const float w1r = cos2pi((float)jj * (1.0f / 256.0f));
        const float w1i = sin2pi((float)jj * (1.0f / 256.0f));
        const float w8r = cos2pi((float)jj * (1.0f / 32.0f));
        const float w8i = sin2pi((float)jj * (1.0f / 32.0f));
        float wr = w1r, wi = w1i;
        #pragma unroll
        for (int q = 1; q < 16; ++q) {
            CMUL2(q, wr, wi)
            if (q == 7) { wr = w8r; wi = w8i; }
            else        { WMUL(wr, wi, w1r, w1i) }
        }
        #pragma unroll
        for (int q = 0; q < 16; ++q)
            lds[SW(base + 16 * q)] = make_float4(xr0[q], xi0[q], xr1[q], xi1[q]);
    }
    __syncthreads();

    // ---- stage 2 fused with epilogue (nibble-swapped ownership) ----
    // Thread t runs the butterfly of former-thread ns = nibbleswap(t); its 8
    // pruned outputs are natural n = (4+i2)*256 + t -> store direct.
    {
        const int ns = ((tid & 15) << 4) | (tid >> 4);   // nibble-swap
        const int base = ns << 4;
        const int f2 = (ns ^ (ns >> 4)) & 15;
        #pragma unroll
        for (int q = 0; q < 16; ++q) {
            float4 v = lds[base + (q ^ f2)];             // == lds[SW(base+q)]
            xr0[q] = v.x; xi0[q] = v.y; xr1[q] = v.z; xi1[q] = v.w;
        }
        float yr0[8], yi0[8], yr1[8], yi1[8];
        dft16_mid8<1>(xr0, xi0, yr0, yi0);
        dft16_mid8<1>(xr1, xi1, yr1, yi1);
        #pragma unroll
        for (int i2 = 0; i2 < 8; ++i2) {
            const float m0 = yr0[i2] * yr0[i2] + yi0[i2] * yi0[i2];
            const float m1 = yr1[i2] * yr1[i2] + yi1[i2] * yi1[i2];
            const float v0 = HALF_LN2 * __builtin_amdgcn_logf(m0) - LOGN;
            const float v1 = HALF_LN2 * __builtin_amdgcn_logf(m1) - LOGN;
            ((float2*)orow)[tid + 256 * i2] = make_float2(v0, v1);
        }
    }
    #undef CMUL2
}

// -------------------- persistent fused kernel --------------------------------
// 512 blocks x 256 threads (2/CU, LDS-limited); atomic task queue.  Tasks
// [0,B) = fwd rows; [B, B+B*NS) = inv pairs, b-major.  flags[b] (release store
// after threadfence+barrier; acquire spin with s_sleep) gates inv on F[b].
// Deadlock-free for ANY residency >= 1: the counter is monotonic and fwd
// tasks never wait, so a block holding an inv task proves all fwd tasks were
// grabbed earlier by blocks that will complete them.  Removes the 64-block
// idle-machine fwd phase and the inter-kernel drain gap.  Sync scheme already
// correctness-validated in R6 (passed, absmax 0.03125); R6's 256-VGPR spill
// is attributed to the (now-deleted) band-skip branch, not this structure.
__global__ __launch_bounds__(256) void fused_kernel(const float* __restrict__ in,
                                                    const float* __restrict__ wft,
                                                    float* __restrict__ out,
                                                    float2* __restrict__ F,
                                                    unsigned* __restrict__ ctrl,
                                                    int B, int NS) {
    __shared__ float4 lds4[NF];                  // 64 KB -> 2 blocks/CU
    __shared__ unsigned s_t;
    unsigned* flags = ctrl;                      // [0, B)
    unsigned* counter = ctrl + 256;              // separate cache line
    const int tid = threadIdx.x;
    const unsigned nFwd = (unsigned)B;
    const unsigned nTot = nFwd + (unsigned)(B * NS);

    for (;;) {
        __syncthreads();                         // LDS + s_t reuse guard
        if (tid == 0) s_t = atomicAdd(counter, 1u);
        __syncthreads();
        const unsigned t = s_t;
        if (t >= nTot) break;                    // uniform exit

        if (t < nFwd) {
            fwd_body(in, F, (float2*)lds4, (int)t, tid);
            __threadfence();                     // publish F writes device-wide
            __syncthreads();
            if (tid == 0)
                __hip_atomic_store(&flags[t], 1u, __ATOMIC_RELEASE,
                                   __HIP_MEMORY_SCOPE_AGENT);
        } else {
            const unsigned p = t - nFwd;
            const int b = (int)(p / (unsigned)NS);
            const int j = (int)(p - (unsigned)b * (unsigned)NS);
            unsigned f;
            do {
                f = __hip_atomic_load(&flags[b], __ATOMIC_ACQUIRE,
                                      __HIP_MEMORY_SCOPE_AGENT);
                if (!f) __builtin_amdgcn_s_sleep(8);
            } while (!f);
            inv_body(F, wft, out, lds4, b, j, tid, NS);
        }
    }
}

extern "C" void kernel_launch(void* const* d_in, const int* in_sizes, int n_in,
                              void* d_out, int out_size, void* d_ws, size_t ws_size,
                              hipStream_t stream) {
    const float* inputs = (const float*)d_in[0];
    const float* wft = (const float*)d_in[1];
    float* out = (float*)d_out;

    const int B = in_sizes[0] / TT;     // 64
    const int NS = in_sizes[1] / NN;    // 75

    float2* F = (float2*)d_ws;                                   // B*4096 cplx = 2 MB
    unsigned* ctrl = (unsigned*)((char*)d_ws + (size_t)B * NF * sizeof(float2));

    hipMemsetAsync(ctrl, 0, 2048, stream);                       // flags + counter
    hipLaunchKernelGGL(fused_kernel, dim3(512), dim3(256), 0, stream,
                       inputs, wft, out, F, ctrl, B, NS);
}

// Round 9
// 132.694 us; speedup vs baseline: 24.2526x; 2.8236x over previous
//
#include <hip/hip_runtime.h>

#define TT 4096          // signal length
#define NN 8192          // padded length
#define NF 4096          // FFT length = 16^3

// XOR swizzle: permutes low 4 bits by a hash of the row; measured ~2% LDS
// bank-conflict overhead across all access patterns used here.
#define SW(i) ((i) ^ ((((i) >> 4) ^ ((i) >> 8)) & 15))

// packed pair of floats: signal-0 component in .x, signal-1 in .y.
// All dual-signal arithmetic on pf is lane-pure -> LLVM can select
// v_pk_{add,mul,fma}_f32 (VOP3P, gfx90a+), halving VALU issue.
typedef __attribute__((ext_vector_type(2))) float pf;

// LDS element: (re0, re1, im0, im1) -- packed pairs contiguous so a
// ds_read_b128 lands each pair in an aligned VGPR pair (no repack movs).
struct alignas(16) c2 { pf r, i; };

// hardware sin/cos of 2*pi*x (x in revolutions); args here are exact dyadics
__device__ __forceinline__ float sin2pi(float x) { return __builtin_amdgcn_sinf(x); }
__device__ __forceinline__ float cos2pi(float x) { return __builtin_amdgcn_cosf(x); }

// (ar,ai) *= (br,bi) -- scalar complex mul (twiddle recurrences)
#define WMUL(ar, ai, br, bi) { float _t = (ar)*(br) - (ai)*(bi); \
                               (ai) = (ar)*(bi) + (ai)*(br); (ar) = _t; }

// e^{i*2*pi/32} — step for k -> k+256 at N=8192
#define C32 0.9807852804032304f
#define S32 0.19509032201612825f

// -------------------- register DFT16 (two radix-4 layers, DIT) --------------
// S = -1: forward (e^{-i}), S = +1: inverse (e^{+i}).  T = float (single
// signal) or pf (dual signal, packed).
template<int S, typename T>
__device__ __forceinline__ void dft4(T& ar, T& ai, T& br, T& bi,
                                     T& cr, T& ci, T& er, T& ei) {
    T t0r = ar + cr, t0i = ai + ci;
    T t1r = ar - cr, t1i = ai - ci;
    T t2r = br + er, t2i = bi + ei;
    T t3r = br - er, t3i = bi - ei;
    ar = t0r + t2r; ai = t0i + t2i;
    cr = t0r - t2r; ci = t0i - t2i;
    br = t1r - (float)S * t3i; bi = t1i + (float)S * t3r;
    er = t1r + (float)S * t3i; ei = t1i - (float)S * t3r;
}

template<int S, typename T>
__device__ __forceinline__ void tmuls16(T xr[16], T xi[16]) {
    const float C1 = 0.9238795325112867f;   // cos(pi/8)
    const float S1 = 0.3826834323650898f;   // sin(pi/8)
    const float R2 = 0.7071067811865476f;
    #define TM(idx, wr, wi) { T _r = xr[idx]*(wr) - xi[idx]*(wi); \
                              xi[idx] = xr[idx]*(wi) + xi[idx]*(wr); xr[idx] = _r; }
    TM(5,  C1,  (float)S * S1)
    TM(9,  R2,  (float)S * R2)
    TM(13, S1,  (float)S * C1)
    TM(6,  R2,  (float)S * R2)
    { T _r = -(float)S * xi[10]; xi[10] = (float)S * xr[10]; xr[10] = _r; }
    TM(14, -R2, (float)S * R2)
    TM(7,  S1,  (float)S * C1)
    TM(11, -R2, (float)S * R2)
    TM(15, -C1, -(float)S * S1)
    #undef TM
}

template<int S, typename T>
__device__ __forceinline__ void dft16(T xr[16], T xi[16]) {
    #pragma unroll
    for (int n0 = 0; n0 < 4; ++n0)
        dft4<S>(xr[n0], xi[n0], xr[n0 + 4], xi[n0 + 4],
                xr[n0 + 8], xi[n0 + 8], xr[n0 + 12], xi[n0 + 12]);

    tmuls16<S>(xr, xi);

    #pragma unroll
    for (int k0 = 0; k0 < 4; ++k0)
        dft4<S>(xr[4*k0], xi[4*k0], xr[4*k0+1], xi[4*k0+1],
                xr[4*k0+2], xi[4*k0+2], xr[4*k0+3], xi[4*k0+3]);

    T tr[16], ti[16];
    #pragma unroll
    for (int q = 0; q < 16; ++q) { int p = 4*(q & 3) + (q >> 2); tr[q] = xr[p]; ti[q] = xi[p]; }
    #pragma unroll
    for (int q = 0; q < 16; ++q) { xr[q] = tr[q]; xi[q] = ti[q]; }
}

// Post-DFT twiddle: x[q] *= w^q with w given by (w1r,w1i); exact reset to
// w^8 = (w8r,w8i) at the midpoint caps the recurrence chain at 7 muls.
// Twiddle recurrence is SCALAR (shared by both packed lanes).
template<typename T>
__device__ __forceinline__ void twiddle16(T xr[16], T xi[16],
                                          float w1r, float w1i,
                                          float w8r, float w8i) {
    float wr = w1r, wi = w1i;
    #pragma unroll
    for (int q = 1; q < 16; ++q) {
        T _r = xr[q]*wr - xi[q]*wi;
        xi[q] = xr[q]*wi + xi[q]*wr; xr[q] = _r;
        if (q == 7) { wr = w8r; wi = w8i; }
        else        { WMUL(wr, wi, w1r, w1i) }
    }
}

// Pruned final-stage DFT16: only natural outputs q in [4,12) are ever needed.
// Output transpose p = 4*(q&3)+(q>>2) means we need only the "b" (q=4+k0) and
// "c" (q=8+k0) outputs of each second-layer dft4.
template<int S, typename T>
__device__ __forceinline__ void dft16_mid8(T xr[16], T xi[16],
                                           T yr[8], T yi[8]) {
    #pragma unroll
    for (int n0 = 0; n0 < 4; ++n0)
        dft4<S>(xr[n0], xi[n0], xr[n0 + 4], xi[n0 + 4],
                xr[n0 + 8], xi[n0 + 8], xr[n0 + 12], xi[n0 + 12]);

    tmuls16<S>(xr, xi);

    #pragma unroll
    for (int k0 = 0; k0 < 4; ++k0) {
        T ar = xr[4*k0],     ai = xi[4*k0];
        T br = xr[4*k0 + 1], bi = xi[4*k0 + 1];
        T cr = xr[4*k0 + 2], ci = xi[4*k0 + 2];
        T er = xr[4*k0 + 3], ei = xi[4*k0 + 3];
        T t0r = ar + cr, t0i = ai + ci;
        T t1r = ar - cr, t1i = ai - ci;
        T t2r = br + er, t2i = bi + ei;
        T t3r = br - er, t3i = bi - ei;
        yr[k0]     = t1r - (float)S * t3i;  yi[k0]     = t1i + (float)S * t3r;  // q = 4+k0
        yr[4 + k0] = t0r - t2r;             yi[4 + k0] = t0i - t2i;             // q = 8+k0
    }
}

__device__ __forceinline__ int refl(int p) {
    if (p < 2048) return 2047 - p;
    if (p < 6144) return p - 2048;
    return 10239 - p;
}

// -------------------- forward: real-8192 FFT via packed complex-4096 ---------
// Verbatim R2 math via the T=float template instantiations.
__global__ __launch_bounds__(256) void fwd_kernel(const float* __restrict__ in,
                                                  float2* __restrict__ F) {
    __shared__ float2 lds[NF];
    const int b = blockIdx.x, tid = threadIdx.x;
    const float* row = in + b * TT;

    float xr[16], xi[16];

    // ---- staging + stage 0 (stride 256), fused in registers ----
    #pragma unroll
    for (int r = 0; r < 16; ++r) {
        const int i = tid + 256 * r;
        xr[r] = row[refl(2 * i)];
        xi[r] = row[refl(2 * i + 1)];
    }
    dft16<-1>(xr, xi);
    twiddle16(xr, xi,
              cos2pi((float)tid * (1.0f / 4096.0f)), -sin2pi((float)tid * (1.0f / 4096.0f)),
              cos2pi((float)tid * (1.0f / 512.0f)),  -sin2pi((float)tid * (1.0f / 512.0f)));
    #pragma unroll
    for (int q = 0; q < 16; ++q) lds[SW(tid + 256 * q)] = make_float2(xr[q], xi[q]);
    __syncthreads();

    // ---- stage 1 (stride 16) ----
    {
        const int j = tid & 15;
        const int base = ((tid >> 4) << 8) + j;
        #pragma unroll
        for (int q = 0; q < 16; ++q) {
            float2 v = lds[SW(base + 16 * q)];
            xr[q] = v.x; xi[q] = v.y;
        }
        dft16<-1>(xr, xi);
        twiddle16(xr, xi,
                  cos2pi((float)j * (1.0f / 256.0f)), -sin2pi((float)j * (1.0f / 256.0f)),
                  cos2pi((float)j * (1.0f / 32.0f)),  -sin2pi((float)j * (1.0f / 32.0f)));
        #pragma unroll
        for (int q = 0; q < 16; ++q) lds[SW(base + 16 * q)] = make_float2(xr[q], xi[q]);
    }
    __syncthreads();

    // ---- stage 2 (twiddle-free) + natural-order scatter ----
    {
        const int base = tid << 4;
        const int fx = (tid ^ (tid >> 4)) & 15;
        #pragma unroll
        for (int q = 0; q < 16; ++q) {
            float2 v = lds[base + (q ^ fx)];
            xr[q] = v.x; xi[q] = v.y;
        }
        dft16<-1>(xr, xi);
        __syncthreads();
        const int c = tid & 15;
        const int h = tid >> 4;
        #pragma unroll
        for (int q = 0; q < 16; ++q)
            lds[(q << 8) + (c << 4) + (h ^ c ^ q)] = make_float2(xr[q], xi[q]);
    }
    __syncthreads();

    // ---- epilogue: unpack real FFT; twiddle (c,s) by recurrence over r ----
    {
        const float c0 = cos2pi((float)(tid + 1) * (1.0f / 8192.0f));
        const float s0 = sin2pi((float)(tid + 1) * (1.0f / 8192.0f));
        float cc = c0, ss = s0;
        #pragma unroll
        for (int r = 0; r < 16; ++r) {
            const int i = tid + 256 * r;
            const int k = i + 1;
            const float2 za = lds[SW(k & (NF - 1))];
            const float2 zb = lds[SW((NF - k) & (NF - 1))];
            const float fer = 0.5f * (za.x + zb.x), fei = 0.5f * (za.y - zb.y);
            const float fo_r = 0.5f * (za.y + zb.y), fo_i = -0.5f * (za.x - zb.x);
            F[b * NF + i] = make_float2(fer + cc * fo_r + ss * fo_i,
                                        fei + cc * fo_i - ss * fo_r);
            if (r == 7) { cc = -s0; ss = c0; }        // exact: * e^{i*pi/2}
            else        { WMUL(cc, ss, C32, S32) }
        }
    }
}

// -------------------- inverse: one block per (batch, scale) ------------------
// d_k = F[b,k]*wft[j,k+1]; half-band 8192-IFFT = two 4096-IFFTs (signal0 =
// even samples, signal1 = odd) computed TOGETHER as packed-pair (pf) math.
// R9 = R2 body with the dual-signal scalar streams replaced by ext_vector
// float2 values: per-lane arithmetic identical (absmax unchanged), VALU issue
// ~halved where LLVM selects v_pk_{add,mul,fma}_f32.  Same 2 barriers, same
// LDS volume (64 KB), stage 2 fused with the epilogue via nibble-swap.
__global__ __launch_bounds__(256) void inv_kernel(const float2* __restrict__ F,
                                                  const float* __restrict__ wft,
                                                  float* __restrict__ out,
                                                  int NS) {
    __shared__ c2 lds[NF];                     // 64 KB -> 2 blocks/CU
    const int blk = blockIdx.x;
    const int b = blk / NS;
    const int j = blk - b * NS;
    const int tid = threadIdx.x;

    const float2* Frow = F + b * NF;
    const float* wrow = wft + (size_t)j * NN + 1;
    float* orow = out + (size_t)(b * NS + j) * TT;
    const float LOGN = 9.0109131020007136f;       // log(8192)
    const float HALF_LN2 = 0.34657359027997264f;  // 0.5 * ln(2)

    pf xr[16], xi[16];

    // ---- staging + stage 0 (stride 256), fused in registers ----
    // d0 = F*w ; d1 = d0 * e^{+2*pi*i*k/8192}, k = tid + 256*r.  The pair
    // (d0, d1) becomes one pf per component.  Rotation advances by exact
    // e^{i*2pi/32} per r; exact e^{i*pi/2} reset at r=8 (scalar recurrence).
    {
        const float c0 = cos2pi((float)tid * (1.0f / 8192.0f));
        const float s0 = sin2pi((float)tid * (1.0f / 8192.0f));
        float cr = c0, ci = s0;
        #pragma unroll
        for (int r = 0; r < 16; ++r) {
            const int k = tid + 256 * r;
            const float2 f = Frow[k];
            const float w = wrow[k];
            const float d0r = f.x * w, d0i = f.y * w;
            pf vr, vi;
            vr.x = d0r;  vr.y = d0r * cr - d0i * ci;
            vi.x = d0i;  vi.y = d0r * ci + d0i * cr;
            xr[r] = vr;  xi[r] = vi;
            if (r == 7) { cr = -s0; ci = c0; }
            else        { WMUL(cr, ci, C32, S32) }
        }
    }
    dft16<1>(xr, xi);
    twiddle16(xr, xi,
              cos2pi((float)tid * (1.0f / 4096.0f)), sin2pi((float)tid * (1.0f / 4096.0f)),
              cos2pi((float)tid * (1.0f / 512.0f)),  sin2pi((float)tid * (1.0f / 512.0f)));
    #pragma unroll
    for (int q = 0; q < 16; ++q) {
        c2 v; v.r = xr[q]; v.i = xi[q];
        lds[SW(tid + 256 * q)] = v;
    }
    __syncthreads();

    // ---- stage 1: stride 16, jj = tid&15 ----
    {
        const int jj = tid & 15;
        const int base = ((tid >> 4) << 8) + jj;
        #pragma unroll
        for (int q = 0; q < 16; ++q) {
            c2 v = lds[SW(base + 16 * q)];
            xr[q] = v.r; xi[q] = v.i;
        }
        dft16<1>(xr, xi);
        twiddle16(xr, xi,
                  cos2pi((float)jj * (1.0f / 256.0f)), sin2pi((float)jj * (1.0f / 256.0f)),
                  cos2pi((float)jj * (1.0f / 32.0f)),  sin2pi((float)jj * (1.0f / 32.0f)));
        #pragma unroll
        for (int q = 0; q < 16; ++q) {
            c2 v; v.r = xr[q]; v.i = xi[q];
            lds[SW(base + 16 * q)] = v;
        }
    }
    __syncthreads();

    // ---- stage 2 fused with epilogue (nibble-swapped ownership) ----
    // Thread t runs the butterfly of former-thread ns = nibbleswap(t); its 8
    // pruned outputs are natural n = (4+i2)*256 + t -> store direct.
    {
        const int ns = ((tid & 15) << 4) | (tid >> 4);   // nibble-swap
        const int base = ns << 4;
        const int fx = (ns ^ (ns >> 4)) & 15;
        #pragma unroll
        for (int q = 0; q < 16; ++q) {
            c2 v = lds[base + (q ^ fx)];                 // == lds[SW(base+q)]
            xr[q] = v.r; xi[q] = v.i;
        }
        pf yr[8], yi[8];
        dft16_mid8<1>(xr, xi, yr, yi);
        #pragma unroll
        for (int i2 = 0; i2 < 8; ++i2) {
            const pf m = yr[i2] * yr[i2] + yi[i2] * yi[i2];
            const float v0 = HALF_LN2 * __builtin_amdgcn_logf(m.x) - LOGN;
            const float v1 = HALF_LN2 * __builtin_amdgcn_logf(m.y) - LOGN;
            ((float2*)orow)[tid + 256 * i2] = make_float2(v0, v1);
        }
    }
}

extern "C" void kernel_launch(void* const* d_in, const int* in_sizes, int n_in,
                              void* d_out, int out_size, void* d_ws, size_t ws_size,
                              hipStream_t stream) {
    const float* inputs = (const float*)d_in[0];
    const float* wft = (const float*)d_in[1];
    float* out = (float*)d_out;

    const int B = in_sizes[0] / TT;     // 64
    const int NS = in_sizes[1] / NN;    // 75

    float2* F = (float2*)d_ws;          // B*4096 complex = 2 MB

    hipLaunchKernelGGL(fwd_kernel, dim3(B), dim3(256), 0, stream, inputs, F);
    hipLaunchKernelGGL(inv_kernel, dim3(B * NS), dim3(256), 0, stream, F, wft, out, NS);
}

// Round 10
// 131.985 us; speedup vs baseline: 24.3830x; 1.0054x over previous
//
#include <hip/hip_runtime.h>

#define TT 4096          // signal length
#define NN 8192          // padded length
#define NF 4096          // FFT length = 16^3

// XOR swizzle (generic form, used only in the fwd epilogue where the index
// does not decompose cleanly).  For i = 256A + 16B + j (A,B,j < 16):
//   SW(i) = 256A + 16B + (j ^ A ^ B)   -- used in closed form in the stages.
#define SW(i) ((i) ^ ((((i) >> 4) ^ ((i) >> 8)) & 15))

// packed pair of floats: signal-0 component in .x, signal-1 in .y.
// All dual-signal arithmetic on pf is lane-pure -> LLVM selects
// v_pk_{add,mul,fma}_f32 (VOP3P), halving VALU issue.
typedef __attribute__((ext_vector_type(2))) float pf;

// LDS element: (re0, re1, im0, im1) -- measured 0 bank conflicts (R9).
struct alignas(16) c2 { pf r, i; };

// hardware sin/cos of 2*pi*x (x in revolutions); args here are exact dyadics
__device__ __forceinline__ float sin2pi(float x) { return __builtin_amdgcn_sinf(x); }
__device__ __forceinline__ float cos2pi(float x) { return __builtin_amdgcn_cosf(x); }

// (ar,ai) *= (br,bi) -- scalar complex mul (twiddle recurrences)
#define WMUL(ar, ai, br, bi) { float _t = (ar)*(br) - (ai)*(bi); \
                               (ai) = (ar)*(bi) + (ai)*(br); (ar) = _t; }

// e^{i*2*pi/32} — step for k -> k+256 at N=8192
#define C32 0.9807852804032304f
#define S32 0.19509032201612825f

// Output-slot permutation of the no-permute DFT16: natural output q lives in
// register slot PQ[q] = 4*(q&3) + (q>>2) (an involution).  Consumers index
// through PQ instead of physically transposing registers (saves 32 packed
// movs per dft16).
__device__ __constant__ const int PQ[16] =
    {0, 4, 8, 12, 1, 5, 9, 13, 2, 6, 10, 14, 3, 7, 11, 15};

// -------------------- register DFT16 (two radix-4 layers, DIT) --------------
// S = -1: forward (e^{-i}), S = +1: inverse (e^{+i}).  T = float or pf.
template<int S, typename T>
__device__ __forceinline__ void dft4(T& ar, T& ai, T& br, T& bi,
                                     T& cr, T& ci, T& er, T& ei) {
    T t0r = ar + cr, t0i = ai + ci;
    T t1r = ar - cr, t1i = ai - ci;
    T t2r = br + er, t2i = bi + ei;
    T t3r = br - er, t3i = bi - ei;
    ar = t0r + t2r; ai = t0i + t2i;
    cr = t0r - t2r; ci = t0i - t2i;
    br = t1r - (float)S * t3i; bi = t1i + (float)S * t3r;
    er = t1r + (float)S * t3i; ei = t1i - (float)S * t3r;
}

template<int S, typename T>
__device__ __forceinline__ void tmuls16(T xr[16], T xi[16]) {
    const float C1 = 0.9238795325112867f;   // cos(pi/8)
    const float S1 = 0.3826834323650898f;   // sin(pi/8)
    const float R2 = 0.7071067811865476f;
    #define TM(idx, wr, wi) { T _r = xr[idx]*(wr) - xi[idx]*(wi); \
                              xi[idx] = xr[idx]*(wi) + xi[idx]*(wr); xr[idx] = _r; }
    TM(5,  C1,  (float)S * S1)
    TM(9,  R2,  (float)S * R2)
    TM(13, S1,  (float)S * C1)
    TM(6,  R2,  (float)S * R2)
    { T _r = -(float)S * xi[10]; xi[10] = (float)S * xr[10]; xr[10] = _r; }
    TM(14, -R2, (float)S * R2)
    TM(7,  S1,  (float)S * C1)
    TM(11, -R2, (float)S * R2)
    TM(15, -C1, -(float)S * S1)
    #undef TM
}

// No-permute DFT16: natural output q is left in slot PQ[q].
template<int S, typename T>
__device__ __forceinline__ void dft16_np(T xr[16], T xi[16]) {
    #pragma unroll
    for (int n0 = 0; n0 < 4; ++n0)
        dft4<S>(xr[n0], xi[n0], xr[n0 + 4], xi[n0 + 4],
                xr[n0 + 8], xi[n0 + 8], xr[n0 + 12], xi[n0 + 12]);

    tmuls16<S>(xr, xi);

    #pragma unroll
    for (int k0 = 0; k0 < 4; ++k0)
        dft4<S>(xr[4*k0], xi[4*k0], xr[4*k0+1], xi[4*k0+1],
                xr[4*k0+2], xi[4*k0+2], xr[4*k0+3], xi[4*k0+3]);
}

// Post-DFT twiddle on no-permute layout: applies w^q to slot PQ[q].
// Scalar recurrence (shared by both packed lanes); exact reset to w^8 at the
// midpoint caps the chain at 7 muls.
template<typename T>
__device__ __forceinline__ void twiddle16_p(T xr[16], T xi[16],
                                            float w1r, float w1i,
                                            float w8r, float w8i) {
    float wr = w1r, wi = w1i;
    #pragma unroll
    for (int q = 1; q < 16; ++q) {
        const int p = PQ[q];
        T _r = xr[p]*wr - xi[p]*wi;
        xi[p] = xr[p]*wi + xi[p]*wr; xr[p] = _r;
        if (q == 7) { wr = w8r; wi = w8i; }
        else        { WMUL(wr, wi, w1r, w1i) }
    }
}

// Pruned final-stage DFT16 (natural inputs): only natural outputs q in [4,12)
// are needed.  y[i2] corresponds to natural output q = 4+i2.
template<int S, typename T>
__device__ __forceinline__ void dft16_mid8(T xr[16], T xi[16],
                                           T yr[8], T yi[8]) {
    #pragma unroll
    for (int n0 = 0; n0 < 4; ++n0)
        dft4<S>(xr[n0], xi[n0], xr[n0 + 4], xi[n0 + 4],
                xr[n0 + 8], xi[n0 + 8], xr[n0 + 12], xi[n0 + 12]);

    tmuls16<S>(xr, xi);

    #pragma unroll
    for (int k0 = 0; k0 < 4; ++k0) {
        T ar = xr[4*k0],     ai = xi[4*k0];
        T br = xr[4*k0 + 1], bi = xi[4*k0 + 1];
        T cr = xr[4*k0 + 2], ci = xi[4*k0 + 2];
        T er = xr[4*k0 + 3], ei = xi[4*k0 + 3];
        T t0r = ar + cr, t0i = ai + ci;
        T t1r = ar - cr, t1i = ai - ci;
        T t2r = br + er, t2i = bi + ei;
        T t3r = br - er, t3i = bi - ei;
        yr[k0]     = t1r - (float)S * t3i;  yi[k0]     = t1i + (float)S * t3r;  // q = 4+k0
        yr[4 + k0] = t0r - t2r;             yi[4 + k0] = t0i - t2i;             // q = 8+k0
    }
}

__device__ __forceinline__ int refl(int p) {
    if (p < 2048) return 2047 - p;
    if (p < 6144) return p - 2048;
    return 10239 - p;
}

// -------------------- forward: real-8192 FFT via packed complex-4096 ---------
// Same math as R2; swizzled addresses in closed form:
//   physical(256A + 16B + jj) = 256A + 16B + (cx ^ q-part), cx = jj ^ h.
__global__ __launch_bounds__(256) void fwd_kernel(const float* __restrict__ in,
                                                  float2* __restrict__ F) {
    __shared__ float2 lds[NF];
    const int b = blockIdx.x, tid = threadIdx.x;
    const int jj = tid & 15, h = tid >> 4, cx = jj ^ h;
    const float* row = in + b * TT;

    float xr[16], xi[16];

    // ---- staging + stage 0 (stride 256), fused in registers ----
    #pragma unroll
    for (int r = 0; r < 16; ++r) {
        const int i = tid + 256 * r;
        xr[r] = row[refl(2 * i)];
        xi[r] = row[refl(2 * i + 1)];
    }
    dft16_np<-1>(xr, xi);
    twiddle16_p(xr, xi,
                cos2pi((float)tid * (1.0f / 4096.0f)), -sin2pi((float)tid * (1.0f / 4096.0f)),
                cos2pi((float)tid * (1.0f / 512.0f)),  -sin2pi((float)tid * (1.0f / 512.0f)));
    // natural-q value (slot PQ[q]) -> linear tid + 256q -> physical:
    #pragma unroll
    for (int q = 0; q < 16; ++q)
        lds[(q << 8) + (h << 4) + (cx ^ q)] = make_float2(xr[PQ[q]], xi[PQ[q]]);
    __syncthreads();

    // ---- stage 1 (stride 16) ----
    {
        #pragma unroll
        for (int q = 0; q < 16; ++q) {
            float2 v = lds[(h << 8) + (q << 4) + (cx ^ q)];
            xr[q] = v.x; xi[q] = v.y;
        }
        dft16_np<-1>(xr, xi);
        twiddle16_p(xr, xi,
                    cos2pi((float)jj * (1.0f / 256.0f)), -sin2pi((float)jj * (1.0f / 256.0f)),
                    cos2pi((float)jj * (1.0f / 32.0f)),  -sin2pi((float)jj * (1.0f / 32.0f)));
        #pragma unroll
        for (int q = 0; q < 16; ++q)
            lds[(h << 8) + (q << 4) + (cx ^ q)] = make_float2(xr[PQ[q]], xi[PQ[q]]);
    }
    __syncthreads();

    // ---- stage 2 (twiddle-free) + natural-order scatter ----
    {
        #pragma unroll
        for (int q = 0; q < 16; ++q) {
            float2 v = lds[(h << 8) + (jj << 4) + (cx ^ q)];
            xr[q] = v.x; xi[q] = v.y;
        }
        dft16_np<-1>(xr, xi);
        __syncthreads();
        // natural q (slot PQ[q]) -> linear 256q + 16jj + h -> physical:
        #pragma unroll
        for (int q = 0; q < 16; ++q)
            lds[(q << 8) + (jj << 4) + (cx ^ q)] = make_float2(xr[PQ[q]], xi[PQ[q]]);
    }
    __syncthreads();

    // ---- epilogue: unpack real FFT; twiddle (c,s) by recurrence over r ----
    {
        const float c0 = cos2pi((float)(tid + 1) * (1.0f / 8192.0f));
        const float s0 = sin2pi((float)(tid + 1) * (1.0f / 8192.0f));
        float cc = c0, ss = s0;
        #pragma unroll
        for (int r = 0; r < 16; ++r) {
            const int i = tid + 256 * r;
            const int k = i + 1;
            const float2 za = lds[SW(k & (NF - 1))];
            const float2 zb = lds[SW((NF - k) & (NF - 1))];
            const float fer = 0.5f * (za.x + zb.x), fei = 0.5f * (za.y - zb.y);
            const float fo_r = 0.5f * (za.y + zb.y), fo_i = -0.5f * (za.x - zb.x);
            F[b * NF + i] = make_float2(fer + cc * fo_r + ss * fo_i,
                                        fei + cc * fo_i - ss * fo_r);
            if (r == 7) { cc = -s0; ss = c0; }        // exact: * e^{i*pi/2}
            else        { WMUL(cc, ss, C32, S32) }
        }
    }
}

// -------------------- inverse: one block per (batch, scale) ------------------
// d_k = F[b,k]*wft[j,k+1]; half-band 8192-IFFT = two 4096-IFFTs (signal0 =
// even samples, signal1 = odd) as packed-pair (pf) math.  R10 = R9 with
// (a) closed-form swizzle addresses (~2 VALU/access vs ~7 for generic SW)
// and (b) no-permute DFT16 (consumers index slot PQ[q]; transpose movs gone).
// Data placement and per-lane arithmetic bit-identical to R9.
__global__ __launch_bounds__(256) void inv_kernel(const float2* __restrict__ F,
                                                  const float* __restrict__ wft,
                                                  float* __restrict__ out,
                                                  int NS) {
    __shared__ c2 lds[NF];                     // 64 KB -> 2 blocks/CU
    const int blk = blockIdx.x;
    const int b = blk / NS;
    const int j = blk - b * NS;
    const int tid = threadIdx.x;
    const int jj = tid & 15, h = tid >> 4, cx = jj ^ h;

    const float2* Frow = F + b * NF;
    const float* wrow = wft + (size_t)j * NN + 1;
    float* orow = out + (size_t)(b * NS + j) * TT;
    const float LOGN = 9.0109131020007136f;       // log(8192)
    const float HALF_LN2 = 0.34657359027997264f;  // 0.5 * ln(2)

    pf xr[16], xi[16];

    // ---- staging + stage 0 (stride 256), fused in registers ----
    // d0 = F*w ; d1 = d0 * e^{+2*pi*i*k/8192}, k = tid + 256*r.  Rotation
    // advances by exact e^{i*2pi/32} per r; exact e^{i*pi/2} reset at r=8.
    {
        const float c0 = cos2pi((float)tid * (1.0f / 8192.0f));
        const float s0 = sin2pi((float)tid * (1.0f / 8192.0f));
        float cr = c0, ci = s0;
        #pragma unroll
        for (int r = 0; r < 16; ++r) {
            const int k = tid + 256 * r;
            const float2 f = Frow[k];
            const float w = wrow[k];
            const float d0r = f.x * w, d0i = f.y * w;
            pf vr, vi;
            vr.x = d0r;  vr.y = d0r * cr - d0i * ci;
            vi.x = d0i;  vi.y = d0r * ci + d0i * cr;
            xr[r] = vr;  xi[r] = vi;
            if (r == 7) { cr = -s0; ci = c0; }
            else        { WMUL(cr, ci, C32, S32) }
        }
    }
    dft16_np<1>(xr, xi);
    twiddle16_p(xr, xi,
                cos2pi((float)tid * (1.0f / 4096.0f)), sin2pi((float)tid * (1.0f / 4096.0f)),
                cos2pi((float)tid * (1.0f / 512.0f)),  sin2pi((float)tid * (1.0f / 512.0f)));
    // natural-q value (slot PQ[q]) at linear tid + 256q -> physical:
    #pragma unroll
    for (int q = 0; q < 16; ++q) {
        c2 v; v.r = xr[PQ[q]]; v.i = xi[PQ[q]];
        lds[(q << 8) + (h << 4) + (cx ^ q)] = v;
    }
    __syncthreads();

    // ---- stage 1: stride 16 ----
    {
        #pragma unroll
        for (int q = 0; q < 16; ++q) {
            c2 v = lds[(h << 8) + (q << 4) + (cx ^ q)];
            xr[q] = v.r; xi[q] = v.i;
        }
        dft16_np<1>(xr, xi);
        twiddle16_p(xr, xi,
                    cos2pi((float)jj * (1.0f / 256.0f)), sin2pi((float)jj * (1.0f / 256.0f)),
                    cos2pi((float)jj * (1.0f / 32.0f)),  sin2pi((float)jj * (1.0f / 32.0f)));
        #pragma unroll
        for (int q = 0; q < 16; ++q) {
            c2 v; v.r = xr[PQ[q]]; v.i = xi[PQ[q]];
            lds[(h << 8) + (q << 4) + (cx ^ q)] = v;
        }
    }
    __syncthreads();

    // ---- stage 2 fused with epilogue (nibble-swapped ownership) ----
    // Thread t runs the butterfly of former-thread ns = nibbleswap(t); its 8
    // pruned outputs are natural n = (4+i2)*256 + t -> store direct.
    // Read: physical(ns*16 + q) = 256jj + 16h + (cx^q).
    {
        #pragma unroll
        for (int q = 0; q < 16; ++q) {
            c2 v = lds[(jj << 8) + (h << 4) + (cx ^ q)];
            xr[q] = v.r; xi[q] = v.i;
        }
        pf yr[8], yi[8];
        dft16_mid8<1>(xr, xi, yr, yi);
        #pragma unroll
        for (int i2 = 0; i2 < 8; ++i2) {
            const pf m = yr[i2] * yr[i2] + yi[i2] * yi[i2];
            const float v0 = HALF_LN2 * __builtin_amdgcn_logf(m.x) - LOGN;
            const float v1 = HALF_LN2 * __builtin_amdgcn_logf(m.y) - LOGN;
            ((float2*)orow)[tid + 256 * i2] = make_float2(v0, v1);
        }
    }
}

extern "C" void kernel_launch(void* const* d_in, const int* in_sizes, int n_in,
                              void* d_out, int out_size, void* d_ws, size_t ws_size,
                              hipStream_t stream) {
    const float* inputs = (const float*)d_in[0];
    const float* wft = (const float*)d_in[1];
    float* out = (float*)d_out;

    const int B = in_sizes[0] / TT;     // 64
    const int NS = in_sizes[1] / NN;    // 75

    float2* F = (float2*)d_ws;          // B*4096 complex = 2 MB

    hipLaunchKernelGGL(fwd_kernel, dim3(B), dim3(256), 0, stream, inputs, F);
    hipLaunchKernelGGL(inv_kernel, dim3(B * NS), dim3(256), 0, stream, F, wft, out, NS);
}

// Round 11
// 130.208 us; speedup vs baseline: 24.7156x; 1.0136x over previous
//
#include <hip/hip_runtime.h>

#define TT 4096          // signal length
#define NN 8192          // padded length
#define NF 4096          // FFT length = 16^3

// XOR swizzle (generic form, used only in the fwd epilogue where the index
// does not decompose cleanly).  For i = 256A + 16B + j (A,B,j < 16):
//   SW(i) = 256A + 16B + (j ^ A ^ B)   -- used in closed form in the stages.
#define SW(i) ((i) ^ ((((i) >> 4) ^ ((i) >> 8)) & 15))

// packed pair of floats: signal-0 component in .x, signal-1 in .y.
// All dual-signal arithmetic on pf is lane-pure -> LLVM selects
// v_pk_{add,mul,fma}_f32 (VOP3P), halving VALU issue.
typedef __attribute__((ext_vector_type(2))) float pf;

// hardware sin/cos of 2*pi*x (x in revolutions); args here are exact dyadics
__device__ __forceinline__ float sin2pi(float x) { return __builtin_amdgcn_sinf(x); }
__device__ __forceinline__ float cos2pi(float x) { return __builtin_amdgcn_cosf(x); }

// (ar,ai) *= (br,bi) -- scalar complex mul (twiddle recurrences)
#define WMUL(ar, ai, br, bi) { float _t = (ar)*(br) - (ai)*(bi); \
                               (ai) = (ar)*(bi) + (ai)*(br); (ar) = _t; }

// e^{i*2*pi/32} — step for k -> k+256 at N=8192
#define C32 0.9807852804032304f
#define S32 0.19509032201612825f

// Output-slot permutation of the no-permute DFT16: natural output q lives in
// register slot PQ[q] = 4*(q&3) + (q>>2) (an involution).  Consumers index
// through PQ instead of physically transposing registers.
__device__ __constant__ const int PQ[16] =
    {0, 4, 8, 12, 1, 5, 9, 13, 2, 6, 10, 14, 3, 7, 11, 15};

// -------------------- register DFT16 (two radix-4 layers, DIT) --------------
// S = -1: forward (e^{-i}), S = +1: inverse (e^{+i}).  T = float or pf.
template<int S, typename T>
__device__ __forceinline__ void dft4(T& ar, T& ai, T& br, T& bi,
                                     T& cr, T& ci, T& er, T& ei) {
    T t0r = ar + cr, t0i = ai + ci;
    T t1r = ar - cr, t1i = ai - ci;
    T t2r = br + er, t2i = bi + ei;
    T t3r = br - er, t3i = bi - ei;
    ar = t0r + t2r; ai = t0i + t2i;
    cr = t0r - t2r; ci = t0i - t2i;
    br = t1r - (float)S * t3i; bi = t1i + (float)S * t3r;
    er = t1r + (float)S * t3i; ei = t1i - (float)S * t3r;
}

template<int S, typename T>
__device__ __forceinline__ void tmuls16(T xr[16], T xi[16]) {
    const float C1 = 0.9238795325112867f;   // cos(pi/8)
    const float S1 = 0.3826834323650898f;   // sin(pi/8)
    const float R2 = 0.7071067811865476f;
    #define TM(idx, wr, wi) { T _r = xr[idx]*(wr) - xi[idx]*(wi); \
                              xi[idx] = xr[idx]*(wi) + xi[idx]*(wr); xr[idx] = _r; }
    TM(5,  C1,  (float)S * S1)
    TM(9,  R2,  (float)S * R2)
    TM(13, S1,  (float)S * C1)
    TM(6,  R2,  (float)S * R2)
    { T _r = -(float)S * xi[10]; xi[10] = (float)S * xr[10]; xr[10] = _r; }
    TM(14, -R2, (float)S * R2)
    TM(7,  S1,  (float)S * C1)
    TM(11, -R2, (float)S * R2)
    TM(15, -C1, -(float)S * S1)
    #undef TM
}

// No-permute DFT16: natural output q is left in slot PQ[q].
template<int S, typename T>
__device__ __forceinline__ void dft16_np(T xr[16], T xi[16]) {
    #pragma unroll
    for (int n0 = 0; n0 < 4; ++n0)
        dft4<S>(xr[n0], xi[n0], xr[n0 + 4], xi[n0 + 4],
                xr[n0 + 8], xi[n0 + 8], xr[n0 + 12], xi[n0 + 12]);

    tmuls16<S>(xr, xi);

    #pragma unroll
    for (int k0 = 0; k0 < 4; ++k0)
        dft4<S>(xr[4*k0], xi[4*k0], xr[4*k0+1], xi[4*k0+1],
                xr[4*k0+2], xi[4*k0+2], xr[4*k0+3], xi[4*k0+3]);
}

// Post-DFT twiddle on no-permute layout: applies w^q to slot PQ[q].
// Scalar recurrence (shared by both packed lanes); exact reset to w^8 at the
// midpoint caps the chain at 7 muls.
template<typename T>
__device__ __forceinline__ void twiddle16_p(T xr[16], T xi[16],
                                            float w1r, float w1i,
                                            float w8r, float w8i) {
    float wr = w1r, wi = w1i;
    #pragma unroll
    for (int q = 1; q < 16; ++q) {
        const int p = PQ[q];
        T _r = xr[p]*wr - xi[p]*wi;
        xi[p] = xr[p]*wi + xi[p]*wr; xr[p] = _r;
        if (q == 7) { wr = w8r; wi = w8i; }
        else        { WMUL(wr, wi, w1r, w1i) }
    }
}

// Pruned final-stage DFT16 (natural inputs): only natural outputs q in [4,12)
// are needed.  y[i2] corresponds to natural output q = 4+i2.
template<int S, typename T>
__device__ __forceinline__ void dft16_mid8(T xr[16], T xi[16],
                                           T yr[8], T yi[8]) {
    #pragma unroll
    for (int n0 = 0; n0 < 4; ++n0)
        dft4<S>(xr[n0], xi[n0], xr[n0 + 4], xi[n0 + 4],
                xr[n0 + 8], xi[n0 + 8], xr[n0 + 12], xi[n0 + 12]);

    tmuls16<S>(xr, xi);

    #pragma unroll
    for (int k0 = 0; k0 < 4; ++k0) {
        T ar = xr[4*k0],     ai = xi[4*k0];
        T br = xr[4*k0 + 1], bi = xi[4*k0 + 1];
        T cr = xr[4*k0 + 2], ci = xi[4*k0 + 2];
        T er = xr[4*k0 + 3], ei = xi[4*k0 + 3];
        T t0r = ar + cr, t0i = ai + ci;
        T t1r = ar - cr, t1i = ai - ci;
        T t2r = br + er, t2i = bi + ei;
        T t3r = br - er, t3i = bi - ei;
        yr[k0]     = t1r - (float)S * t3i;  yi[k0]     = t1i + (float)S * t3r;  // q = 4+k0
        yr[4 + k0] = t0r - t2r;             yi[4 + k0] = t0i - t2i;             // q = 8+k0
    }
}

__device__ __forceinline__ int refl(int p) {
    if (p < 2048) return 2047 - p;
    if (p < 6144) return p - 2048;
    return 10239 - p;
}

// -------------------- forward: real-8192 FFT via packed complex-4096 ---------
// Unchanged from R10 (64 blocks; not the bottleneck).
__global__ __launch_bounds__(256) void fwd_kernel(const float* __restrict__ in,
                                                  float2* __restrict__ F) {
    __shared__ float2 lds[NF];
    const int b = blockIdx.x, tid = threadIdx.x;
    const int jj = tid & 15, h = tid >> 4, cx = jj ^ h;
    const float* row = in + b * TT;

    float xr[16], xi[16];

    // ---- staging + stage 0 (stride 256), fused in registers ----
    #pragma unroll
    for (int r = 0; r < 16; ++r) {
        const int i = tid + 256 * r;
        xr[r] = row[refl(2 * i)];
        xi[r] = row[refl(2 * i + 1)];
    }
    dft16_np<-1>(xr, xi);
    twiddle16_p(xr, xi,
                cos2pi((float)tid * (1.0f / 4096.0f)), -sin2pi((float)tid * (1.0f / 4096.0f)),
                cos2pi((float)tid * (1.0f / 512.0f)),  -sin2pi((float)tid * (1.0f / 512.0f)));
    #pragma unroll
    for (int q = 0; q < 16; ++q)
        lds[(q << 8) + (h << 4) + (cx ^ q)] = make_float2(xr[PQ[q]], xi[PQ[q]]);
    __syncthreads();

    // ---- stage 1 (stride 16) ----
    {
        #pragma unroll
        for (int q = 0; q < 16; ++q) {
            float2 v = lds[(h << 8) + (q << 4) + (cx ^ q)];
            xr[q] = v.x; xi[q] = v.y;
        }
        dft16_np<-1>(xr, xi);
        twiddle16_p(xr, xi,
                    cos2pi((float)jj * (1.0f / 256.0f)), -sin2pi((float)jj * (1.0f / 256.0f)),
                    cos2pi((float)jj * (1.0f / 32.0f)),  -sin2pi((float)jj * (1.0f / 32.0f)));
        #pragma unroll
        for (int q = 0; q < 16; ++q)
            lds[(h << 8) + (q << 4) + (cx ^ q)] = make_float2(xr[PQ[q]], xi[PQ[q]]);
    }
    __syncthreads();

    // ---- stage 2 (twiddle-free) + natural-order scatter ----
    {
        #pragma unroll
        for (int q = 0; q < 16; ++q) {
            float2 v = lds[(h << 8) + (jj << 4) + (cx ^ q)];
            xr[q] = v.x; xi[q] = v.y;
        }
        dft16_np<-1>(xr, xi);
        __syncthreads();
        #pragma unroll
        for (int q = 0; q < 16; ++q)
            lds[(q << 8) + (jj << 4) + (cx ^ q)] = make_float2(xr[PQ[q]], xi[PQ[q]]);
    }
    __syncthreads();

    // ---- epilogue: unpack real FFT; twiddle (c,s) by recurrence over r ----
    {
        const float c0 = cos2pi((float)(tid + 1) * (1.0f / 8192.0f));
        const float s0 = sin2pi((float)(tid + 1) * (1.0f / 8192.0f));
        float cc = c0, ss = s0;
        #pragma unroll
        for (int r = 0; r < 16; ++r) {
            const int i = tid + 256 * r;
            const int k = i + 1;
            const float2 za = lds[SW(k & (NF - 1))];
            const float2 zb = lds[SW((NF - k) & (NF - 1))];
            const float fer = 0.5f * (za.x + zb.x), fei = 0.5f * (za.y - zb.y);
            const float fo_r = 0.5f * (za.y + zb.y), fo_i = -0.5f * (za.x - zb.x);
            F[b * NF + i] = make_float2(fer + cc * fo_r + ss * fo_i,
                                        fei + cc * fo_i - ss * fo_r);
            if (r == 7) { cc = -s0; ss = c0; }        // exact: * e^{i*pi/2}
            else        { WMUL(cc, ss, C32, S32) }
        }
    }
}

// -------------------- inverse: one block per (batch, scale) ------------------
// d_k = F[b,k]*wft[j,k+1]; half-band 8192-IFFT = two 4096-IFFTs (signal0 =
// even samples, signal1 = odd) as packed-pair (pf) math.
// R11: each LDS transpose is time-multiplexed PER PACKED COMPONENT through a
// single 32 KB pf buffer (write-re, bar, read-re, bar, write-im, bar,
// read-im): re/im planes are independent during pure data movement, reads
// land in the slots the writes just freed (zero extra registers), addresses
// are the verified R10 closed forms.  LDS 64 KB -> 32 KB lifts residency
// from 2 to 5 blocks/CU (20 waves/CU; VGPR 88 allows exactly 5 waves/SIMD).
// Cost: 7 barriers (vs 2) + 32 extra ds_b64 ops, covered by 5 resident blocks.
__global__ __launch_bounds__(256) void inv_kernel(const float2* __restrict__ F,
                                                  const float* __restrict__ wft,
                                                  float* __restrict__ out,
                                                  int NS) {
    __shared__ pf lds[NF];                     // 32 KB -> 5 blocks/CU
    const int blk = blockIdx.x;
    const int b = blk / NS;
    const int j = blk - b * NS;
    const int tid = threadIdx.x;
    const int jj = tid & 15, h = tid >> 4, cx = jj ^ h;

    const float2* Frow = F + b * NF;
    const float* wrow = wft + (size_t)j * NN + 1;
    float* orow = out + (size_t)(b * NS + j) * TT;
    const float LOGN = 9.0109131020007136f;       // log(8192)
    const float HALF_LN2 = 0.34657359027997264f;  // 0.5 * ln(2)

    pf xr[16], xi[16];

    // ---- staging + stage 0 (stride 256), fused in registers ----
    // d0 = F*w ; d1 = d0 * e^{+2*pi*i*k/8192}, k = tid + 256*r.  Rotation
    // advances by exact e^{i*2pi/32} per r; exact e^{i*pi/2} reset at r=8.
    {
        const float c0 = cos2pi((float)tid * (1.0f / 8192.0f));
        const float s0 = sin2pi((float)tid * (1.0f / 8192.0f));
        float cr = c0, ci = s0;
        #pragma unroll
        for (int r = 0; r < 16; ++r) {
            const int k = tid + 256 * r;
            const float2 f = Frow[k];
            const float w = wrow[k];
            const float d0r = f.x * w, d0i = f.y * w;
            pf vr, vi;
            vr.x = d0r;  vr.y = d0r * cr - d0i * ci;
            vi.x = d0i;  vi.y = d0r * ci + d0i * cr;
            xr[r] = vr;  xi[r] = vi;
            if (r == 7) { cr = -s0; ci = c0; }
            else        { WMUL(cr, ci, C32, S32) }
        }
    }
    dft16_np<1>(xr, xi);
    twiddle16_p(xr, xi,
                cos2pi((float)tid * (1.0f / 4096.0f)), sin2pi((float)tid * (1.0f / 4096.0f)),
                cos2pi((float)tid * (1.0f / 512.0f)),  sin2pi((float)tid * (1.0f / 512.0f)));

    // ---- transpose T1 (stage0 -> stage1), component-split through 32 KB ----
    // natural-q value (slot PQ[q]) at linear tid + 256q -> physical address.
    #pragma unroll
    for (int q = 0; q < 16; ++q)
        lds[(q << 8) + (h << 4) + (cx ^ q)] = xr[PQ[q]];
    __syncthreads();
    #pragma unroll
    for (int q = 0; q < 16; ++q)
        xr[q] = lds[(h << 8) + (q << 4) + (cx ^ q)];
    __syncthreads();
    #pragma unroll
    for (int q = 0; q < 16; ++q)
        lds[(q << 8) + (h << 4) + (cx ^ q)] = xi[PQ[q]];
    __syncthreads();
    #pragma unroll
    for (int q = 0; q < 16; ++q)
        xi[q] = lds[(h << 8) + (q << 4) + (cx ^ q)];
    __syncthreads();

    // ---- stage 1 (stride 16) ----
    dft16_np<1>(xr, xi);
    twiddle16_p(xr, xi,
                cos2pi((float)jj * (1.0f / 256.0f)), sin2pi((float)jj * (1.0f / 256.0f)),
                cos2pi((float)jj * (1.0f / 32.0f)),  sin2pi((float)jj * (1.0f / 32.0f)));

    // ---- transpose T2 (stage1 -> stage2), component-split ----
    // Write at linear 256h + 16q + jj; read with nibble-swapped ownership:
    // thread t gathers physical(ns*16 + q), ns = nibbleswap(t).
    #pragma unroll
    for (int q = 0; q < 16; ++q)
        lds[(h << 8) + (q << 4) + (cx ^ q)] = xr[PQ[q]];
    __syncthreads();
    #pragma unroll
    for (int q = 0; q < 16; ++q)
        xr[q] = lds[(jj << 8) + (h << 4) + (cx ^ q)];
    __syncthreads();
    #pragma unroll
    for (int q = 0; q < 16; ++q)
        lds[(h << 8) + (q << 4) + (cx ^ q)] = xi[PQ[q]];
    __syncthreads();
    #pragma unroll
    for (int q = 0; q < 16; ++q)
        xi[q] = lds[(jj << 8) + (h << 4) + (cx ^ q)];

    // ---- stage 2 fused with epilogue (nibble-swapped ownership) ----
    // Thread t's 8 pruned outputs are natural n = (4+i2)*256 + t -> store direct.
    {
        pf yr[8], yi[8];
        dft16_mid8<1>(xr, xi, yr, yi);
        #pragma unroll
        for (int i2 = 0; i2 < 8; ++i2) {
            const pf m = yr[i2] * yr[i2] + yi[i2] * yi[i2];
            const float v0 = HALF_LN2 * __builtin_amdgcn_logf(m.x) - LOGN;
            const float v1 = HALF_LN2 * __builtin_amdgcn_logf(m.y) - LOGN;
            ((float2*)orow)[tid + 256 * i2] = make_float2(v0, v1);
        }
    }
}

extern "C" void kernel_launch(void* const* d_in, const int* in_sizes, int n_in,
                              void* d_out, int out_size, void* d_ws, size_t ws_size,
                              hipStream_t stream) {
    const float* inputs = (const float*)d_in[0];
    const float* wft = (const float*)d_in[1];
    float* out = (float*)d_out;

    const int B = in_sizes[0] / TT;     // 64
    const int NS = in_sizes[1] / NN;    // 75

    float2* F = (float2*)d_ws;          // B*4096 complex = 2 MB

    hipLaunchKernelGGL(fwd_kernel, dim3(B), dim3(256), 0, stream, inputs, F);
    hipLaunchKernelGGL(inv_kernel, dim3(B * NS), dim3(256), 0, stream, F, wft, out, NS);
}